// Round 3
// baseline (100.581 us; speedup 1.0000x reference)
//
#include <hip/hip_runtime.h>

// Problem constants
#define B_    8
#define CIN_  16
#define COUT_ 32
#define DIN_  24
#define PDIM_ 11               // pooled output spatial dim
#define XCH_  (DIN_*DIN_*DIN_) // 13824 elems per (b,cin) channel
#define WEFF_N (CIN_*27*COUT_) // 13824
#define NSPATIAL (B_*PDIM_*PDIM_*PDIM_) // 10648
#define CHUNKS 167             // ceil(NSPATIAL / 64)

// Kernel 1: build effective weights + folded affine constants.
// weff layout: [(cin*27 + tap)*32 + co], scaled by gamma/sqrt(var+eps)/64.
__global__ __launch_bounds__(256) void prep_kernel(
    const float* __restrict__ w,      // (CIN, COUT, 3,3,3)
    const float* __restrict__ bias,
    const float* __restrict__ gamma,
    const float* __restrict__ beta,
    const float* __restrict__ rmean,
    const float* __restrict__ rvar,
    float* __restrict__ weff,
    float* __restrict__ bconst)
{
    int idx = blockIdx.x * 256 + threadIdx.x;   // [0, 13824), exact
    int co  = idx & 31;
    int tap = (idx >> 5) % 27;
    int cin = idx / (27 * 32);
    int dd = tap / 9, dh = (tap / 3) % 3, dw = tap % 3;
    // valid kernel taps per di: di=0 -> {1,2}, di=1 -> {0,1,2}, di=2 -> {0}
    const int klo[3] = {1, 0, 0};
    const int khi[3] = {2, 2, 0};
    const float* wb = w + (cin * COUT_ + co) * 27;
    float s = 0.f;
    for (int kd = klo[dd]; kd <= khi[dd]; ++kd)
        for (int kh = klo[dh]; kh <= khi[dh]; ++kh)
            for (int kw = klo[dw]; kw <= khi[dw]; ++kw)
                s += wb[kd * 9 + kh * 3 + kw];
    float scale = gamma[co] * rsqrtf(rvar[co] + 1e-5f);
    weff[idx] = s * scale * (1.0f / 64.0f);
    if (blockIdx.x == 0 && threadIdx.x < COUT_) {
        int c = threadIdx.x;
        float sc = gamma[c] * rsqrtf(rvar[c] + 1e-5f);
        bconst[c] = bias[c] * sc + beta[c] - rmean[c] * sc;
    }
}

// Kernel 2: fused stride-2 3x3x3 conv producing the pooled output directly.
// 512 threads = 8 waves: wave = (cin_half, co_octet). Lanes = 64 consecutive
// spatial outputs. cin-half-1 waves dump partials to LDS; half-0 waves combine.
__global__ __launch_bounds__(512) void conv_kernel(
    const float* __restrict__ x,       // (B, CIN, 24,24,24)
    const float* __restrict__ weff,    // [(cin*27+tap)*32 + co]
    const float* __restrict__ bconst,
    float* __restrict__ out)           // (B, COUT, 11,11,11)
{
    __shared__ float part[8 * 256];    // [j][octet*64+lane], conflict-free

    const int lane = threadIdx.x & 63;
    // readfirstlane keeps wave id in an SGPR -> weight addresses stay scalar
    const int wv    = __builtin_amdgcn_readfirstlane(threadIdx.x >> 6); // 0..7
    const int octet = wv & 3;
    const int half  = wv >> 2;             // 0: cin 0-7, 1: cin 8-15
    const int co_base = octet * 8;

    unsigned g = blockIdx.x * 64u + (unsigned)lane;
    const bool valid = g < NSPATIAL;
    const unsigned gg = valid ? g : 0u;
    const unsigned b  = gg / 1331u;
    const unsigned r  = gg - b * 1331u;      // pd*121 + ph*11 + pw
    const unsigned pd = r / 121u;
    const unsigned r2 = r - pd * 121u;
    const unsigned ph = r2 / 11u;
    const unsigned pw = r2 - ph * 11u;

    // per-lane x base at (b, cin=0, 2pd, 2ph, 2pw); element offset is even
    const float* xb = x + (size_t)b * (CIN_ * XCH_)
                        + pd * (2 * DIN_ * DIN_) + ph * (2 * DIN_) + pw * 2;
    const float* wb = weff + co_base;        // scalar

    float acc[8];
    #pragma unroll
    for (int j = 0; j < 8; ++j) acc[j] = 0.f;

    const int cin0 = half * 8;
    for (int ci = 0; ci < 8; ++ci) {
        const int cin = cin0 + ci;
        const float* xc = xb + cin * XCH_;
        const float* wc = wb + cin * (27 * 32);
        #pragma unroll
        for (int dd = 0; dd < 3; ++dd) {
            #pragma unroll
            for (int dh = 0; dh < 3; ++dh) {
                const float* xr = xc + dd * (DIN_ * DIN_) + dh * DIN_;
                // 3 consecutive floats, 8B-aligned: float2 + float
                const float2 x01 = *(const float2*)xr;
                const float  x2  = xr[2];
                const float xv[3] = {x01.x, x01.y, x2};
                #pragma unroll
                for (int dw = 0; dw < 3; ++dw) {
                    const float* wt = wc + (dd * 9 + dh * 3 + dw) * 32;
                    #pragma unroll
                    for (int j = 0; j < 8; ++j)
                        acc[j] = fmaf(xv[dw], wt[j], acc[j]);
                }
            }
        }
    }

    const int slot = octet * 64 + lane;
    if (half == 1) {
        #pragma unroll
        for (int j = 0; j < 8; ++j) part[j * 256 + slot] = acc[j];
    }
    __syncthreads();
    if (half == 0 && valid) {
        float* ob = out + ((size_t)b * COUT_ + co_base) * 1331 + r;
        #pragma unroll
        for (int j = 0; j < 8; ++j)
            ob[(size_t)j * 1331] = acc[j] + part[j * 256 + slot] + bconst[co_base + j];
    }
}

extern "C" void kernel_launch(void* const* d_in, const int* in_sizes, int n_in,
                              void* d_out, int out_size, void* d_ws, size_t ws_size,
                              hipStream_t stream) {
    const float* x      = (const float*)d_in[0];
    const float* weight = (const float*)d_in[1];
    const float* bias   = (const float*)d_in[2];
    const float* gamma  = (const float*)d_in[3];
    const float* beta   = (const float*)d_in[4];
    const float* rmean  = (const float*)d_in[5];
    const float* rvar   = (const float*)d_in[6];
    float* out = (float*)d_out;

    float* weff   = (float*)d_ws;
    float* bconst = weff + WEFF_N;

    // 54 * 256 == 13824 exactly
    prep_kernel<<<WEFF_N / 256, 256, 0, stream>>>(weight, bias, gamma, beta,
                                                  rmean, rvar, weff, bconst);
    // one block per 64-spatial chunk; 8 waves = 4 co-octets x 2 cin-halves
    conv_kernel<<<CHUNKS, 512, 0, stream>>>(x, weff, bconst, out);
}

// Round 4
// 93.539 us; speedup vs baseline: 1.0753x; 1.0753x over previous
//
#include <hip/hip_runtime.h>

// Problem constants
#define B_    8
#define CIN_  16
#define COUT_ 32
#define DIN_  24
#define PDIM_ 11               // pooled output spatial dim
#define XCH_  (DIN_*DIN_*DIN_) // 13824 elems per (b,cin) channel
#define WEFF_N (CIN_*27*COUT_) // 13824
#define NSPATIAL (B_*PDIM_*PDIM_*PDIM_) // 10648
#define CHUNKS 167             // ceil(NSPATIAL / 64)

// Kernel 1: build effective weights + folded affine constants.
// weff layout: [(cin*27 + tap)*32 + co], scaled by gamma/sqrt(var+eps)/64.
__global__ __launch_bounds__(256) void prep_kernel(
    const float* __restrict__ w,      // (CIN, COUT, 3,3,3)
    const float* __restrict__ bias,
    const float* __restrict__ gamma,
    const float* __restrict__ beta,
    const float* __restrict__ rmean,
    const float* __restrict__ rvar,
    float* __restrict__ weff,
    float* __restrict__ bconst)
{
    int idx = blockIdx.x * 256 + threadIdx.x;   // [0, 13824), exact
    int co  = idx & 31;
    int tap = (idx >> 5) % 27;
    int cin = idx / (27 * 32);
    int dd = tap / 9, dh = (tap / 3) % 3, dw = tap % 3;
    // valid kernel taps per di: di=0 -> {1,2}, di=1 -> {0,1,2}, di=2 -> {0}
    const int klo[3] = {1, 0, 0};
    const int khi[3] = {2, 2, 0};
    const float* wb = w + (cin * COUT_ + co) * 27;
    float s = 0.f;
    for (int kd = klo[dd]; kd <= khi[dd]; ++kd)
        for (int kh = klo[dh]; kh <= khi[dh]; ++kh)
            for (int kw = klo[dw]; kw <= khi[dw]; ++kw)
                s += wb[kd * 9 + kh * 3 + kw];
    float scale = gamma[co] * rsqrtf(rvar[co] + 1e-5f);
    weff[idx] = s * scale * (1.0f / 64.0f);
    if (blockIdx.x == 0 && threadIdx.x < COUT_) {
        int c = threadIdx.x;
        float sc = gamma[c] * rsqrtf(rvar[c] + 1e-5f);
        bconst[c] = bias[c] * sc + beta[c] - rmean[c] * sc;
    }
}

// Kernel 2: fused stride-2 3x3x3 conv producing the pooled output directly.
// One wave per block (R2 structure — best so far). Lanes = 64 consecutive
// spatial outputs; each thread accumulates 8 output channels. Weight
// addresses are blockIdx-derived (wave-uniform) -> scalar loads; x loads are
// coalesced per-lane. cin loop unrolled x4 so independent loads from 4
// iterations are in flight, hiding memory latency despite <1 wave/SIMD.
__global__ __launch_bounds__(64) void conv_kernel(
    const float* __restrict__ x,       // (B, CIN, 24,24,24)
    const float* __restrict__ weff,    // [(cin*27+tap)*32 + co]
    const float* __restrict__ bconst,
    float* __restrict__ out)           // (B, COUT, 11,11,11)
{
    const int lane   = threadIdx.x;          // 0..63
    const unsigned wid   = blockIdx.x;       // 0..CHUNKS*4-1
    const unsigned chunk = wid >> 2;         // spatial chunk
    const int co_base    = (wid & 3u) * 8;   // uniform (from blockIdx)

    unsigned g = chunk * 64u + (unsigned)lane;
    const bool valid = g < NSPATIAL;
    const unsigned gg = valid ? g : 0u;
    const unsigned b  = gg / 1331u;
    const unsigned r  = gg - b * 1331u;      // pd*121 + ph*11 + pw
    const unsigned pd = r / 121u;
    const unsigned r2 = r - pd * 121u;
    const unsigned ph = r2 / 11u;
    const unsigned pw = r2 - ph * 11u;

    // hoist the (uniform) bias constants so their s_loads issue early
    float bc[8];
    #pragma unroll
    for (int j = 0; j < 8; ++j) bc[j] = bconst[co_base + j];

    // per-lane x base at (b, cin=0, 2pd, 2ph, 2pw)
    const float* xb = x + (size_t)b * (CIN_ * XCH_)
                        + pd * (2 * DIN_ * DIN_) + ph * (2 * DIN_) + pw * 2;
    const float* wb = weff + co_base;        // uniform

    float acc[8];
    #pragma unroll
    for (int j = 0; j < 8; ++j) acc[j] = 0.f;

    #pragma unroll 4
    for (int cin = 0; cin < CIN_; ++cin) {
        const float* xc = xb + cin * XCH_;
        const float* wc = wb + cin * (27 * 32);
        // issue all 9 row loads (18 vmem ops) for this cin up front
        float xv[3][3][3];
        #pragma unroll
        for (int dd = 0; dd < 3; ++dd) {
            #pragma unroll
            for (int dh = 0; dh < 3; ++dh) {
                const float* xr = xc + dd * (DIN_ * DIN_) + dh * DIN_;
                const float2 x01 = *(const float2*)xr;   // 8B-aligned
                xv[dd][dh][0] = x01.x;
                xv[dd][dh][1] = x01.y;
                xv[dd][dh][2] = xr[2];
            }
        }
        #pragma unroll
        for (int dd = 0; dd < 3; ++dd) {
            #pragma unroll
            for (int dh = 0; dh < 3; ++dh) {
                #pragma unroll
                for (int dw = 0; dw < 3; ++dw) {
                    const float* wt = wc + (dd * 9 + dh * 3 + dw) * 32;
                    #pragma unroll
                    for (int j = 0; j < 8; ++j)
                        acc[j] = fmaf(xv[dd][dh][dw], wt[j], acc[j]);
                }
            }
        }
    }

    if (valid) {
        float* ob = out + ((size_t)b * COUT_ + co_base) * 1331 + r;
        #pragma unroll
        for (int j = 0; j < 8; ++j)
            ob[(size_t)j * 1331] = acc[j] + bc[j];
    }
}

extern "C" void kernel_launch(void* const* d_in, const int* in_sizes, int n_in,
                              void* d_out, int out_size, void* d_ws, size_t ws_size,
                              hipStream_t stream) {
    const float* x      = (const float*)d_in[0];
    const float* weight = (const float*)d_in[1];
    const float* bias   = (const float*)d_in[2];
    const float* gamma  = (const float*)d_in[3];
    const float* beta   = (const float*)d_in[4];
    const float* rmean  = (const float*)d_in[5];
    const float* rvar   = (const float*)d_in[6];
    float* out = (float*)d_out;

    float* weff   = (float*)d_ws;
    float* bconst = weff + WEFF_N;

    // 54 * 256 == 13824 exactly
    prep_kernel<<<WEFF_N / 256, 256, 0, stream>>>(weight, bias, gamma, beta,
                                                  rmean, rvar, weff, bconst);
    // CHUNKS spatial chunks x 4 co-octets, one wave per block
    conv_kernel<<<CHUNKS * 4, 64, 0, stream>>>(x, weff, bconst, out);
}

// Round 5
// 93.167 us; speedup vs baseline: 1.0796x; 1.0040x over previous
//
#include <hip/hip_runtime.h>

// Problem constants
#define B_    8
#define CIN_  16
#define COUT_ 32
#define DIN_  24
#define PDIM_ 11               // pooled output spatial dim
#define XCH_  (DIN_*DIN_*DIN_) // 13824 elems per (b,cin) channel
#define WEFF_N (CIN_*27*COUT_) // 13824
#define NSPATIAL (B_*PDIM_*PDIM_*PDIM_) // 10648
#define CHUNKS 167             // ceil(NSPATIAL / 64)

// Kernel 1: build effective weights + folded affine constants.
// weff layout: [(cin*27 + tap)*32 + co], scaled by gamma/sqrt(var+eps)/64.
__global__ __launch_bounds__(256) void prep_kernel(
    const float* __restrict__ w,      // (CIN, COUT, 3,3,3)
    const float* __restrict__ bias,
    const float* __restrict__ gamma,
    const float* __restrict__ beta,
    const float* __restrict__ rmean,
    const float* __restrict__ rvar,
    float* __restrict__ weff,
    float* __restrict__ bconst)
{
    int idx = blockIdx.x * 256 + threadIdx.x;   // [0, 13824), exact
    int co  = idx & 31;
    int tap = (idx >> 5) % 27;
    int cin = idx / (27 * 32);
    int dd = tap / 9, dh = (tap / 3) % 3, dw = tap % 3;
    // valid kernel taps per di: di=0 -> {1,2}, di=1 -> {0,1,2}, di=2 -> {0}
    const int klo[3] = {1, 0, 0};
    const int khi[3] = {2, 2, 0};
    const float* wb = w + (cin * COUT_ + co) * 27;
    float s = 0.f;
    for (int kd = klo[dd]; kd <= khi[dd]; ++kd)
        for (int kh = klo[dh]; kh <= khi[dh]; ++kh)
            for (int kw = klo[dw]; kw <= khi[dw]; ++kw)
                s += wb[kd * 9 + kh * 3 + kw];
    float scale = gamma[co] * rsqrtf(rvar[co] + 1e-5f);
    weff[idx] = s * scale * (1.0f / 64.0f);
    if (blockIdx.x == 0 && threadIdx.x < COUT_) {
        int c = threadIdx.x;
        float sc = gamma[c] * rsqrtf(rvar[c] + 1e-5f);
        bconst[c] = bias[c] * sc + beta[c] - rmean[c] * sc;
    }
}

// Kernel 2: fused stride-2 3x3x3 conv producing the pooled output directly.
// One wave per block. Lanes = 64 consecutive spatial outputs; each thread
// accumulates 8 output channels held as float2[4] so the splat-x * weight-pair
// FMAs can compile to v_pk_fma_f32 (dual fp32 FMA per issue). Weight
// addresses are blockIdx-derived (wave-uniform) -> scalar loads; x loads are
// coalesced per-lane; cin loop unrolled x4 for load ILP.
__global__ __launch_bounds__(64) void conv_kernel(
    const float* __restrict__ x,       // (B, CIN, 24,24,24)
    const float* __restrict__ weff,    // [(cin*27+tap)*32 + co]
    const float* __restrict__ bconst,
    float* __restrict__ out)           // (B, COUT, 11,11,11)
{
    const int lane   = threadIdx.x;          // 0..63
    const unsigned wid   = blockIdx.x;       // 0..CHUNKS*4-1
    const unsigned chunk = wid >> 2;         // spatial chunk
    const int co_base    = (wid & 3u) * 8;   // uniform (from blockIdx)

    unsigned g = chunk * 64u + (unsigned)lane;
    const bool valid = g < NSPATIAL;
    const unsigned gg = valid ? g : 0u;
    const unsigned b  = gg / 1331u;
    const unsigned r  = gg - b * 1331u;      // pd*121 + ph*11 + pw
    const unsigned pd = r / 121u;
    const unsigned r2 = r - pd * 121u;
    const unsigned ph = r2 / 11u;
    const unsigned pw = r2 - ph * 11u;

    // hoist the (uniform) bias constants so their s_loads issue early
    float bc[8];
    #pragma unroll
    for (int j = 0; j < 8; ++j) bc[j] = bconst[co_base + j];

    // per-lane x base at (b, cin=0, 2pd, 2ph, 2pw)
    const float* xb = x + (size_t)b * (CIN_ * XCH_)
                        + pd * (2 * DIN_ * DIN_) + ph * (2 * DIN_) + pw * 2;
    const float* wb = weff + co_base;        // uniform, 32B-aligned

    float2 acc[4];
    #pragma unroll
    for (int q = 0; q < 4; ++q) { acc[q].x = 0.f; acc[q].y = 0.f; }

    #pragma unroll 4
    for (int cin = 0; cin < CIN_; ++cin) {
        const float* xc = xb + cin * XCH_;
        const float* wc = wb + cin * (27 * 32);
        // issue all 9 row loads (18 vmem ops) for this cin up front
        float xv[3][3][3];
        #pragma unroll
        for (int dd = 0; dd < 3; ++dd) {
            #pragma unroll
            for (int dh = 0; dh < 3; ++dh) {
                const float* xr = xc + dd * (DIN_ * DIN_) + dh * DIN_;
                const float2 x01 = *(const float2*)xr;   // 8B-aligned
                xv[dd][dh][0] = x01.x;
                xv[dd][dh][1] = x01.y;
                xv[dd][dh][2] = xr[2];
            }
        }
        #pragma unroll
        for (int dd = 0; dd < 3; ++dd) {
            #pragma unroll
            for (int dh = 0; dh < 3; ++dh) {
                #pragma unroll
                for (int dw = 0; dw < 3; ++dw) {
                    const float xs = xv[dd][dh][dw];
                    const float2* wt2 = (const float2*)(wc + (dd * 9 + dh * 3 + dw) * 32);
                    #pragma unroll
                    for (int q = 0; q < 4; ++q) {
                        const float2 w2 = wt2[q];
                        acc[q].x = fmaf(xs, w2.x, acc[q].x);
                        acc[q].y = fmaf(xs, w2.y, acc[q].y);
                    }
                }
            }
        }
    }

    if (valid) {
        float* ob = out + ((size_t)b * COUT_ + co_base) * 1331 + r;
        #pragma unroll
        for (int q = 0; q < 4; ++q) {
            ob[(size_t)(2 * q)     * 1331] = acc[q].x + bc[2 * q];
            ob[(size_t)(2 * q + 1) * 1331] = acc[q].y + bc[2 * q + 1];
        }
    }
}

extern "C" void kernel_launch(void* const* d_in, const int* in_sizes, int n_in,
                              void* d_out, int out_size, void* d_ws, size_t ws_size,
                              hipStream_t stream) {
    const float* x      = (const float*)d_in[0];
    const float* weight = (const float*)d_in[1];
    const float* bias   = (const float*)d_in[2];
    const float* gamma  = (const float*)d_in[3];
    const float* beta   = (const float*)d_in[4];
    const float* rmean  = (const float*)d_in[5];
    const float* rvar   = (const float*)d_in[6];
    float* out = (float*)d_out;

    float* weff   = (float*)d_ws;
    float* bconst = weff + WEFF_N;

    // 54 * 256 == 13824 exactly
    prep_kernel<<<WEFF_N / 256, 256, 0, stream>>>(weight, bias, gamma, beta,
                                                  rmean, rvar, weff, bconst);
    // CHUNKS spatial chunks x 4 co-octets, one wave per block
    conv_kernel<<<CHUNKS * 4, 64, 0, stream>>>(x, weff, bconst, out);
}